// Round 5
// baseline (6217.239 us; speedup 1.0000x reference)
//
#include <hip/hip_runtime.h>

// B=64, S=256, T=64, E=256, H=256, G=4H=1024, VT=32000
typedef unsigned short u16;
typedef unsigned int u32;
typedef unsigned long long u64;
typedef short s8v __attribute__((ext_vector_type(8)));
typedef float f32x4 __attribute__((ext_vector_type(4)));
typedef unsigned short us4 __attribute__((ext_vector_type(4)));

#define MFMA16(a,b,c) __builtin_amdgcn_mfma_f32_16x16x32_bf16(a,b,c,0,0,0)

__device__ __forceinline__ float b2f(u16 u){ union{u32 i; float f;} v; v.i=((u32)u)<<16; return v.f; }
__device__ __forceinline__ u16 f2b(float f){ union{float f; u32 i;} v; v.f=f; u32 r=v.i+0x7FFFu+((v.i>>16)&1u); return (u16)(r>>16); }
__device__ __forceinline__ float sigf(float x){ return 1.f/(1.f+__expf(-x)); }
__device__ __forceinline__ float tanh_(float x){ x=fminf(15.f,fmaxf(-15.f,x)); float e=__expf(2.f*x); return (e-1.f)/(e+1.f); }
__device__ __forceinline__ float tanhs(float x){ float e=__expf(2.f*x); return 1.f - 2.f/(e+1.f); }

union FU { s8v v; us4 h[2]; };

// sc1 (coherent, bypass L1/L2) helpers: relaxed agent-scope atomics.
__device__ __forceinline__ us4 ld8_sys(const u16* p){
  u64 v = __hip_atomic_load((const u64*)p, __ATOMIC_RELAXED, __HIP_MEMORY_SCOPE_AGENT);
  union{u64 q; us4 h;} x; x.q=v; return x.h;
}
__device__ __forceinline__ float2 ld8f2(const float* p){
  u64 v = __hip_atomic_load((const u64*)p, __ATOMIC_RELAXED, __HIP_MEMORY_SCOPE_AGENT);
  union{u64 q; float2 f;} x; x.q=v; return x.f;
}
__device__ __forceinline__ void st4_sys(u16* p, u32 v){
  __hip_atomic_store((u32*)p, v, __ATOMIC_RELAXED, __HIP_MEMORY_SCOPE_AGENT);
}
__device__ __forceinline__ void st4f(float* p, float v){
  union{float f; u32 i;} u; u.f=v;
  __hip_atomic_store((u32*)p, u.i, __ATOMIC_RELAXED, __HIP_MEMORY_SCOPE_AGENT);
}
__device__ __forceinline__ void st8_sys(u16* p, us4 v){
  union{us4 h; u64 q;} x; x.h=v;
  __hip_atomic_store((u64*)p, x.q, __ATOMIC_RELAXED, __HIP_MEMORY_SCOPE_AGENT);
}
__device__ __forceinline__ int ldcnt(const int* p){
  return __hip_atomic_load(p, __ATOMIC_RELAXED, __HIP_MEMORY_SCOPE_AGENT);
}
__device__ __forceinline__ void addcnt(int* p){
  __hip_atomic_fetch_add(p, 1, __ATOMIC_RELAXED, __HIP_MEMORY_SCOPE_AGENT);
}

// Fragment loaders; A and B use the same k-bijection so the HW k-layout cancels.
__device__ __forceinline__ s8v gfrag(const u16* rowp, int kbase, int g4){
  FU u; const u16* p = rowp + kbase + 4*g4;
  u.h[0] = *(const us4*)p; u.h[1] = *(const us4*)(p+16);
  return u.v;
}
// LDS frag with 8B-granule XOR swizzle (granule ^= row&7).
__device__ __forceinline__ s8v ldsfrag(const u16* lds, int ldk, int row, int kbase, int g4){
  int sw = row&7;
  int g0 = ((kbase+4*g4)>>2)^sw, g1 = ((kbase+16+4*g4)>>2)^sw;
  FU u;
  u.h[0] = *(const us4*)&lds[row*ldk + (g0<<2)];
  u.h[1] = *(const us4*)&lds[row*ldk + (g1<<2)];
  return u.v;
}

// ---------------- prep: f32 -> bf16 weight conversions / relayouts ----------------
__global__ __launch_bounds__(256) void prep_kernel(
    const float* Wihf, const float* Whhf, const float* Wihb, const float* Whhb,
    const float* d0Wih, const float* d0Whh, const float* d1Wih, const float* d1Whh,
    const float* attnW, const float* projW,
    u16* oWihf, u16* oWhhf, u16* oWihb, u16* oWhhb,
    u16* oW0, u16* oW1, u16* oWaH, u16* oWaE, u16* oprojW){
  long long i = (long long)blockIdx.x*256 + threadIdx.x;
  const long long N1 = 262144;
  if (i < N1){ oWihf[i] = f2b(Wihf[i]); return; } i -= N1;
  if (i < N1){ oWhhf[i] = f2b(Whhf[i]); return; } i -= N1;
  if (i < N1){ oWihb[i] = f2b(Wihb[i]); return; } i -= N1;
  if (i < N1){ oWhhb[i] = f2b(Whhb[i]); return; } i -= N1;
  if (i < 1048576){ // W0cat [1024][1024] = [Wih0(768) | Whh0(256)]
    int g = (int)(i>>10), k = (int)(i&1023);
    float v = (k<768) ? d0Wih[(size_t)g*768+k] : d0Whh[(size_t)g*256 + (k-768)];
    oW0[i] = f2b(v); return;
  } i -= 1048576;
  if (i < 524288){ // W1cat [1024][512] = [Wih1(256) | Whh1(256)]
    int g = (int)(i>>9), k = (int)(i&511);
    float v = (k<256) ? d1Wih[(size_t)g*256+k] : d1Whh[(size_t)g*256 + (k-256)];
    oW1[i] = f2b(v); return;
  } i -= 524288;
  if (i < 65536){ int n=(int)(i>>8), k=(int)(i&255); oWaH[i] = f2b(attnW[(size_t)n*768+k]); return; } i -= 65536;
  if (i < 131072){ int n=(int)(i>>9), k=(int)(i&511); oWaE[i] = f2b(attnW[(size_t)n*768+256+k]); return; } i -= 131072;
  if (i < 8192000){ oprojW[i] = f2b(projW[i]); return; }
}

// ---------------- gather ----------------
__global__ __launch_bounds__(256) void gather_kernel(
    const int* src, const int* tgt, const float* src_emb, const float* tgt_emb,
    u16* xs, u16* temb){
  long long i = (long long)blockIdx.x*256 + threadIdx.x;
  if (i < 4194304){
    int e = (int)(i&255); int sb = (int)(i>>8);
    int s = sb>>6, b = sb&63;
    int idx = src[b*256 + s];
    xs[i] = f2b(src_emb[(size_t)idx*256 + e]);
    return;
  }
  long long j = i - 4194304;
  if (j < 1048576){
    int e = (int)(j&255); int tb = (int)(j>>8);
    int t = tb>>6, b = tb&63;
    int idx = tgt[b*64 + t];
    temb[j] = f2b(tgt_emb[(size_t)idx*256 + e]);
  }
}

// ---------------- 64x64-tile MFMA GEMM: C = A @ B^T + bias ----------------
template<int K, int OBF>
__global__ __launch_bounds__(256) void gemm64(
    const u16* __restrict__ A, int lda, const u16* __restrict__ Bw, int ldb,
    const float* __restrict__ bias, void* Cout, long long ldc){
  __shared__ u16 Alds[64*K];
  int tid = threadIdx.x;
  long long mt = blockIdx.x, nt = blockIdx.y;
  const int Kc8 = K>>3;
  for (int it = tid; it < 64*Kc8; it += 256){
    int row = it / Kc8, seg = it % Kc8;
    const u16* src = A + (size_t)(mt*64+row)*lda + seg*8;
    us4 a0 = *(const us4*)src, a1 = *(const us4*)(src+4);
    int sw = row&7;
    *(us4*)&Alds[row*K + ((((seg*2  ))^sw)<<2)] = a0;
    *(us4*)&Alds[row*K + ((((seg*2+1))^sw)<<2)] = a1;
  }
  __syncthreads();
  int w = tid>>6, lane = tid&63;
  int l15 = lane&15, g4 = lane>>4;
  int arow = w*16 + l15;
  const int NKT = K>>5;
  s8v af[NKT];
  #pragma unroll
  for (int kt=0; kt<NKT; ++kt) af[kt] = ldsfrag(Alds, K, arow, kt*32, g4);
  f32x4 acc[4];
  #pragma unroll
  for (int nti=0; nti<4; ++nti){
    const u16* brow = Bw + (size_t)(nt*64 + nti*16 + l15)*ldb;
    f32x4 a = {0.f,0.f,0.f,0.f};
    #pragma unroll
    for (int kt=0; kt<NKT; ++kt) a = MFMA16(af[kt], gfrag(brow, kt*32, g4), a);
    acc[nti] = a;
  }
  #pragma unroll
  for (int nti=0; nti<4; ++nti)
    #pragma unroll
    for (int r=0; r<4; ++r){
      long long rowg = mt*64 + w*16 + 4*g4 + r;
      long long colg = nt*64 + nti*16 + l15;
      float v = acc[nti][r] + bias[colg];
      if (OBF) ((u16*)Cout)[rowg*ldc + colg] = f2b(v);
      else     ((float*)Cout)[rowg*ldc + colg] = v;
    }
}

// ---------------- encoder v3: 16 WGs in pairs, register Whh slice ----------------
// WG: dir=bid&1, bb=(bid>>1)&3 (16 batches), ch=bid>>3 (128 h-cols). Partner = bid^8.
__global__ __launch_bounds__(512,2) void encoder_kernel(
    const u16* __restrict__ XWf, const u16* __restrict__ XWb,
    const u16* __restrict__ Whhf, const u16* __restrict__ Whhb,
    u16* __restrict__ enc_out, float* hTf, float* cTf, float* hTb, float* cTb,
    u16* hx, int* ecnt){
  int bid = blockIdx.x, tid = threadIdx.x;
  int dir = bid&1, bb=(bid>>1)&3, ch=bid>>3;
  const u16* XW  = dir ? XWb : XWf;
  const u16* Whh = dir ? Whhb : Whhf;
  float* hT = dir ? hTb : hTf; float* cT = dir ? cTb : cTf;
  int w = tid>>6, lane = tid&63, l15=lane&15, g4=lane>>4;
  int bg0 = bb*16;
  // wave w owns output tiles t4 = w*4+i : q=t4>>3 (gate), jt=t4&7 (16-col group in our 128)
  s8v bwf[4][8];
  #pragma unroll
  for (int i=0;i<4;++i){
    int t4 = w*4+i, q=t4>>3, jt=t4&7;
    const u16* wr = Whh + (size_t)(q*256 + ch*128 + jt*16 + l15)*256;
    #pragma unroll
    for (int kt=0;kt<8;++kt) bwf[i][kt] = gfrag(wr, kt*32, g4);
  }
  int gb = tid>>5, cl = (tid&31)*4; // gate thread: batch gb, local cols cl..cl+3
  float cst[4]={0.f,0.f,0.f,0.f};
  __shared__ u16 hbuf[16*256];
  __shared__ float gacc[512][17];
  for (int i=tid;i<4096;i+=512) hbuf[i]=0;
  __syncthreads();
  int* myc = &ecnt[bid*32];
  int* pc  = &ecnt[(bid^8)*32];
  u16* myhx = hx + (size_t)bid*2*16*128;
  const u16* phx = hx + (size_t)(bid^8)*2*16*128;
  for (int t=0;t<256;++t){
    int s = dir ? 255-t : t;
    // prefetch XW gate inputs (depends only on s)
    us4 xw4[4];
    const u16* xwr = XW + (((size_t)s*64 + bg0 + gb))*1024 + ch*128 + cl;
    #pragma unroll
    for (int qq=0;qq<4;++qq) xw4[qq] = *(const us4*)(xwr + qq*256);
    // A-frags (batches x K=256)
    s8v af[8];
    #pragma unroll
    for (int kt=0;kt<8;++kt) af[kt] = ldsfrag(hbuf, 256, l15, kt*32, g4);
    #pragma unroll
    for (int i=0;i<4;++i){
      f32x4 a={0.f,0.f,0.f,0.f};
      #pragma unroll
      for (int kt=0;kt<8;++kt) a = MFMA16(af[kt], bwf[i][kt], a);
      int t4=w*4+i, q=t4>>3, jt=t4&7;
      // D mapping: m(batch)=4*g4+r, n(col)=l15. gacc[gate*128+col_local][batch].
      #pragma unroll
      for (int r=0;r<4;++r) gacc[q*128 + jt*16 + l15][4*g4+r] = a[r];
    }
    __syncthreads();
    // gates + LSTM elementwise (all 512 threads, 4 cols each)
    float hvv[4];
    #pragma unroll
    for (int cc=0;cc<4;++cc){
      int clc = cl+cc;
      float gi = gacc[clc][gb]     + b2f(xw4[0][cc]);
      float gf = gacc[128+clc][gb] + b2f(xw4[1][cc]);
      float gg = gacc[256+clc][gb] + b2f(xw4[2][cc]);
      float go = gacc[384+clc][gb] + b2f(xw4[3][cc]);
      float iv=sigf(gi), fv=sigf(gf), gv=tanh_(gg), ov=sigf(go);
      float cn = fv*cst[cc]+iv*gv; cst[cc]=cn;
      hvv[cc] = ov*tanh_(cn);
    }
    us4 hv4;
    #pragma unroll
    for (int cc=0;cc<4;++cc) hv4[cc] = f2b(hvv[cc]);
    *(us4*)&enc_out[(((size_t)(bg0+gb)*256 + s))*512 + dir*256 + ch*128 + cl] = hv4;
    if (t==255){
      #pragma unroll
      for (int cc=0;cc<4;++cc){
        hT[(bg0+gb)*256 + ch*128 + cl+cc] = hvv[cc];
        cT[(bg0+gb)*256 + ch*128 + cl+cc] = cst[cc];
      }
    } else {
      int col = ch*128 + cl;
      *(us4*)&hbuf[gb*256 + ((((col>>2)) ^ (gb&7))<<2)] = hv4;
      st8_sys(myhx + ((size_t)(t&1)*16*128) + gb*128 + cl, hv4);
      asm volatile("s_waitcnt vmcnt(0)" ::: "memory");
      __syncthreads();
      if (tid==0){
        addcnt(myc);
        while (ldcnt(pc) < t+1) __builtin_amdgcn_s_sleep(1);
      }
      __syncthreads();
      // import partner half
      int b2 = tid>>5, cl4 = (tid&31)*4;
      us4 pv = ld8_sys(phx + ((size_t)(t&1)*16*128) + b2*128 + cl4);
      int pcol = (1-ch)*128 + cl4;
      *(us4*)&hbuf[b2*256 + ((((pcol>>2)) ^ (b2&7))<<2)] = pv;
      __syncthreads();
    }
  }
}

// ---------------- init decoder states ----------------
__global__ __launch_bounds__(256) void init_states(
    const float* hTf, const float* hTb, const float* cTf, const float* cTb,
    float* c0g, float* c1g, u16* h0buf, u16* h1buf){
  int i = blockIdx.x*256 + threadIdx.x; // 16384
  float h = hTf[i] + hTb[i];
  float c = cTf[i] + cTb[i];
  c0g[i]=c; c1g[i]=c;
  u16 hb = f2b(h);
  h0buf[16384+i] = hb;  // parity-1 slot (read at tt=0)
  h1buf[16384+i] = hb;
}

// ---------------- decoder v3: 8 independent groups of 16 WGs ----------------
// group g=bid&7: batches 8g..8g+7. WG c=bid>>3: h-cols 16c..16c+15, s-slice [16c,16c+16),
// ctx-dim slice [32c,32c+32). 4 group-local barriers/step.
__global__ __launch_bounds__(512,2) void decoder_kernel(
    const u16* __restrict__ epb, const u16* __restrict__ enc, const u16* __restrict__ temb,
    const u16* __restrict__ WaH, const u16* __restrict__ W0, const u16* __restrict__ W1,
    const float* __restrict__ attn_v, const float* __restrict__ b0, const float* __restrict__ b1,
    const float* __restrict__ c0init, const float* __restrict__ c1init,
    u16* h0buf, u16* h1buf, u16* ctxg, float* scoreg, u16* dout, int* dcnt){
  int bid = blockIdx.x, tid = threadIdx.x;
  int g = bid&7, c = bid>>3;
  int w = tid>>6, lane = tid&63, l15 = lane&15, g4 = lane>>4;
  int bg0 = g*8;
  int q = w&3, kh = w>>2;
  // register-resident weight slices
  s8v b0f[16], b1f[8];
  {
    const u16* w0r = W0 + (size_t)(q*256 + c*16 + l15)*1024 + kh*512;
    const u16* w1r = W1 + (size_t)(q*256 + c*16 + l15)*512  + kh*256;
    #pragma unroll
    for (int kt=0;kt<16;++kt) b0f[kt] = gfrag(w0r, kt*32, g4);
    #pragma unroll
    for (int kt=0;kt<8;++kt)  b1f[kt] = gfrag(w1r, kt*32, g4);
  }
  int cb = tid>>4, ci = tid&15; // gate thread (tid<128): batch cb, col ci
  float c0r=0.f, c1r=0.f, bias0[4], bias1[4];
  if (tid<128){
    c0r = c0init[(bg0+cb)*256 + c*16+ci];
    c1r = c1init[(bg0+cb)*256 + c*16+ci];
    #pragma unroll
    for (int qq=0;qq<4;++qq){ bias0[qq]=b0[qq*256 + c*16+ci]; bias1[qq]=b1[qq*256 + c*16+ci]; }
  }
  __shared__ u16 x0l[16*1024];
  __shared__ u16 x1l[16*512];
  __shared__ u16 h1l[16*256];
  __shared__ float qls[8][257];
  __shared__ float scls[8][257];
  __shared__ float red[8][16][17];
  __shared__ float ctxl[8][33];
  __shared__ float vl[256];
  if (tid<256) vl[tid] = attn_v[tid];
  for (int i=tid;i<8192;i+=512) x0l[8192+i]=0;   // rows 8..15 zero
  for (int i=tid;i<4096;i+=512) x1l[4096+i]=0;
  for (int i=tid;i<2048;i+=512) h1l[2048+i]=0;
  __syncthreads();
  int* cnt = &dcnt[g*32];
  int bt = 0;

#define GBAR() do{ bt += 16; \
    asm volatile("s_waitcnt vmcnt(0)" ::: "memory"); \
    __syncthreads(); \
    if (tid==0){ addcnt(cnt); while (ldcnt(cnt) < bt) __builtin_amdgcn_s_sleep(1); } \
    __syncthreads(); }while(0)

  for (int tt=0; tt<64; ++tt){
    int par = tt&1, pp = par^1;
    // ===== Phase A1: import h1prev; q = h1 @ WaH^T (MFMA); scores for s-slice =====
    {
      int b = tid>>6, c4 = lane*4;
      us4 hv4 = ld8_sys(h1buf + (size_t)pp*16384 + (bg0+b)*256 + c4);
      *(us4*)&h1l[b*256 + ((((c4>>2)) ^ b)<<2)] = hv4;              // b<8 so b&7==b
      int col = 256 + c4;
      *(us4*)&x1l[b*512 + ((((col>>2)) ^ b)<<2)] = hv4;
    }
    __syncthreads();
    #pragma unroll
    for (int t2=0;t2<2;++t2){
      int ct = w*2+t2;
      const u16* br = WaH + (size_t)(ct*16 + l15)*256;
      f32x4 a = {0.f,0.f,0.f,0.f};
      #pragma unroll
      for (int kt=0;kt<8;++kt) a = MFMA16(ldsfrag(h1l,256,l15,kt*32,g4), gfrag(br,kt*32,g4), a);
      #pragma unroll
      for (int r=0;r<4;++r){ int row=4*g4+r; if(row<8) qls[row][ct*16+l15] = a[r]; }
    }
    __syncthreads();
    {
      int pair = tid>>2, k2 = tid&3;
      int b = pair>>4, sl = pair&15, s = c*16+sl;
      const u16* ep = epb + ((size_t)((bg0+b)*256 + s))*256 + k2*64;
      float p = 0.f;
      #pragma unroll 4
      for (int u2=0;u2<16;++u2){
        us4 e4 = *(const us4*)(ep + u2*4);
        #pragma unroll
        for (int jj=0;jj<4;++jj){
          int h = k2*64 + u2*4 + jj;
          p += tanhs(b2f(e4[jj]) + qls[b][h]) * vl[h];
        }
      }
      p += __shfl_xor(p,1); p += __shfl_xor(p,2);
      if (k2==0) st4f(scoreg + (size_t)(bg0+b)*256 + s, p);
    }
    GBAR();
    // ===== Phase A2: softmax (wave-per-batch) + ctx dim-slice =====
    #pragma unroll
    for (int k=0;k<2;++k){
      int idx = tid + k*512;
      int b = idx>>7, s2 = (idx&127)*2;
      float2 f2 = ld8f2(scoreg + (size_t)(bg0+b)*256 + s2);
      scls[b][s2] = f2.x; scls[b][s2+1] = f2.y;
    }
    __syncthreads();
    {
      int b = w;
      float a0=scls[b][lane*4], a1=scls[b][lane*4+1], a2=scls[b][lane*4+2], a3=scls[b][lane*4+3];
      float m = fmaxf(fmaxf(a0,a1),fmaxf(a2,a3));
      #pragma unroll
      for (int o2=32;o2;o2>>=1) m = fmaxf(m, __shfl_xor(m,o2));
      float e0=__expf(a0-m), e1=__expf(a1-m), e2=__expf(a2-m), e3=__expf(a3-m);
      float sm = e0+e1+e2+e3;
      #pragma unroll
      for (int o2=32;o2;o2>>=1) sm += __shfl_xor(sm,o2);
      float inv = 1.f/sm;
      scls[b][lane*4]=e0*inv; scls[b][lane*4+1]=e1*inv; scls[b][lane*4+2]=e2*inv; scls[b][lane*4+3]=e3*inv;
    }
    __syncthreads();
    {
      int pair = tid>>1, sh = tid&1;
      int b = pair>>5, dl = pair&31, d = c*32+dl;
      const u16* ep2 = enc + ((size_t)((bg0+b)*256 + sh*128))*512 + d;
      float cx=0.f;
      #pragma unroll 4
      for (int s3=0;s3<128;++s3) cx += scls[b][sh*128+s3] * b2f(ep2[(size_t)s3*512]);
      cx += __shfl_xor(cx,1);
      if (sh==0) ctxl[b][dl] = cx;
    }
    __syncthreads();
    if (tid<128){
      int b = tid>>4, d2 = (tid&15)*2;
      u32 pk = (u32)f2b(ctxl[b][d2]) | ((u32)f2b(ctxl[b][d2+1])<<16);
      st4_sys(ctxg + (size_t)(bg0+b)*512 + c*32 + d2, pk);
    }
    GBAR();
    // ===== Phase C: assemble x0 = [emb | ctx | h0prev]; dec0 cell =====
    {
      int b = tid>>6, e4 = lane*4;
      us4 tv = *(const us4*)(temb + ((size_t)tt*64 + bg0 + b)*256 + e4);
      *(us4*)&x0l[b*1024 + ((((e4>>2)) ^ b)<<2)] = tv;
    }
    #pragma unroll
    for (int k=0;k<2;++k){
      int idx = tid + k*512;
      int b = idx>>7, c4 = (idx&127)*4;
      us4 cv = ld8_sys(ctxg + (size_t)(bg0+b)*512 + c4);
      int col = 256 + c4;
      *(us4*)&x0l[b*1024 + ((((col>>2)) ^ b)<<2)] = cv;
    }
    {
      int b = tid>>6, c4 = lane*4;
      us4 hv4 = ld8_sys(h0buf + (size_t)pp*16384 + (bg0+b)*256 + c4);
      int col = 768 + c4;
      *(us4*)&x0l[b*1024 + ((((col>>2)) ^ b)<<2)] = hv4;
    }
    __syncthreads();
    {
      f32x4 a={0.f,0.f,0.f,0.f};
      #pragma unroll
      for (int kt=0;kt<16;++kt)
        a = MFMA16(ldsfrag(x0l,1024,l15,kh*512+kt*32,g4), b0f[kt], a);
      #pragma unroll
      for (int r=0;r<4;++r) red[w][4*g4+r][l15] = a[r];
    }
    __syncthreads();
    if (tid<128){
      float gi = red[0][cb][ci]+red[4][cb][ci]+bias0[0];
      float gf = red[1][cb][ci]+red[5][cb][ci]+bias0[1];
      float gg = red[2][cb][ci]+red[6][cb][ci]+bias0[2];
      float go = red[3][cb][ci]+red[7][cb][ci]+bias0[3];
      float iv=sigf(gi), fv=sigf(gf), gv=tanh_(gg), ov=sigf(go);
      float cn = fv*c0r+iv*gv; c0r=cn;
      float hv = ov*tanh_(cn);
      int me=f2b(hv), ot=__shfl_xor(me,1);
      if ((tid&1)==0) st4_sys(h0buf + (size_t)par*16384 + (bg0+cb)*256 + c*16+ci,
                              ((u32)me&0xFFFFu)|((u32)ot<<16));
    }
    GBAR();
    // ===== Phase D: x1 = [h0 | h1prev]; dec1 cell =====
    {
      int b = tid>>6, c4 = lane*4;
      us4 hv4 = ld8_sys(h0buf + (size_t)par*16384 + (bg0+b)*256 + c4);
      *(us4*)&x1l[b*512 + ((((c4>>2)) ^ b)<<2)] = hv4;
    }
    __syncthreads();
    {
      f32x4 a={0.f,0.f,0.f,0.f};
      #pragma unroll
      for (int kt=0;kt<8;++kt)
        a = MFMA16(ldsfrag(x1l,512,l15,kh*256+kt*32,g4), b1f[kt], a);
      #pragma unroll
      for (int r=0;r<4;++r) red[w][4*g4+r][l15] = a[r];
    }
    __syncthreads();
    if (tid<128){
      float gi = red[0][cb][ci]+red[4][cb][ci]+bias1[0];
      float gf = red[1][cb][ci]+red[5][cb][ci]+bias1[1];
      float gg = red[2][cb][ci]+red[6][cb][ci]+bias1[2];
      float go = red[3][cb][ci]+red[7][cb][ci]+bias1[3];
      float iv=sigf(gi), fv=sigf(gf), gv=tanh_(gg), ov=sigf(go);
      float cn = fv*c1r+iv*gv; c1r=cn;
      float hv = ov*tanh_(cn);
      int me=f2b(hv), ot=__shfl_xor(me,1);
      if ((tid&1)==0){
        u32 pk = ((u32)me&0xFFFFu)|((u32)ot<<16);
        st4_sys(h1buf + (size_t)par*16384 + (bg0+cb)*256 + c*16+ci, pk);
        *(u32*)&dout[((size_t)(bg0+cb)*64+tt)*256 + c*16+ci] = pk;
      }
    }
    GBAR();
  }
#undef GBAR
}

// ---------------- host launcher ----------------
extern "C" void kernel_launch(void* const* d_in, const int* in_sizes, int n_in,
                              void* d_out, int out_size, void* d_ws, size_t ws_size,
                              hipStream_t stream){
  const int*   src     = (const int*)  d_in[0];
  const int*   tgt     = (const int*)  d_in[1];
  const float* src_emb = (const float*)d_in[2];
  const float* tgt_emb = (const float*)d_in[3];
  const float* encfWih = (const float*)d_in[4];
  const float* encfWhh = (const float*)d_in[5];
  const float* encfb   = (const float*)d_in[6];
  const float* encbWih = (const float*)d_in[7];
  const float* encbWhh = (const float*)d_in[8];
  const float* encbb   = (const float*)d_in[9];
  const float* d0Wih   = (const float*)d_in[10];
  const float* d0Whh   = (const float*)d_in[11];
  const float* d0b     = (const float*)d_in[12];
  const float* d1Wih   = (const float*)d_in[13];
  const float* d1Whh   = (const float*)d_in[14];
  const float* d1b     = (const float*)d_in[15];
  const float* attnW   = (const float*)d_in[16];
  const float* attnb   = (const float*)d_in[17];
  const float* attnv   = (const float*)d_in[18];
  const float* projW   = (const float*)d_in[19];
  const float* projb   = (const float*)d_in[20];

  char* ws = (char*)d_ws;
  size_t off = 0;
  auto alloc = [&](size_t bytes)->char*{ char* p = ws + off; off += (bytes + 255) & ~(size_t)255; return p; };

  int* dcnt     = (int*)alloc(1024);
  int* ecnt     = (int*)alloc(2048);
  u16* xs       = (u16*)alloc(16384ULL*256*2);
  u16* temb     = (u16*)alloc(4096ULL*256*2);
  u16* oWihf    = (u16*)alloc(262144ULL*2);
  u16* oWhhf    = (u16*)alloc(262144ULL*2);
  u16* oWihb    = (u16*)alloc(262144ULL*2);
  u16* oWhhb    = (u16*)alloc(262144ULL*2);
  u16* oW0      = (u16*)alloc(1048576ULL*2);
  u16* oW1      = (u16*)alloc(524288ULL*2);
  u16* oWaH     = (u16*)alloc(65536ULL*2);
  u16* oWaE     = (u16*)alloc(131072ULL*2);
  u16* oprojW   = (u16*)alloc(8192000ULL*2);
  u16* XWf      = (u16*)alloc(16384ULL*1024*2);
  u16* XWb      = (u16*)alloc(16384ULL*1024*2);
  u16* enc      = (u16*)alloc(64ULL*256*512*2);
  u16* epb      = (u16*)alloc(64ULL*256*256*2);
  float* hTf    = (float*)alloc(16384ULL*4);
  float* cTf    = (float*)alloc(16384ULL*4);
  float* hTb    = (float*)alloc(16384ULL*4);
  float* cTb    = (float*)alloc(16384ULL*4);
  float* c0g    = (float*)alloc(16384ULL*4);
  float* c1g    = (float*)alloc(16384ULL*4);
  u16* h0buf    = (u16*)alloc(2ULL*16384*2);
  u16* h1buf    = (u16*)alloc(2ULL*16384*2);
  u16* ctxg     = (u16*)alloc(64ULL*512*2);
  float* scoreg = (float*)alloc(16384ULL*4);
  u16* hx       = (u16*)alloc(16ULL*2*16*128*2);
  u16* dout     = (u16*)alloc(4096ULL*256*2);
  if (off > ws_size) return;

  hipMemsetAsync(dcnt, 0, 1024, stream);
  hipMemsetAsync(ecnt, 0, 2048, stream);

  prep_kernel<<<43008, 256, 0, stream>>>(encfWih, encfWhh, encbWih, encbWhh,
      d0Wih, d0Whh, d1Wih, d1Whh, attnW, projW,
      oWihf, oWhhf, oWihb, oWhhb, oW0, oW1, oWaH, oWaE, oprojW);

  gather_kernel<<<20480, 256, 0, stream>>>(src, tgt, src_emb, tgt_emb, xs, temb);

  gemm64<256,1><<<dim3(256,16), 256, 0, stream>>>(xs, 256, oWihf, 256, encfb, XWf, 1024);
  gemm64<256,1><<<dim3(256,16), 256, 0, stream>>>(xs, 256, oWihb, 256, encbb, XWb, 1024);

  encoder_kernel<<<16, 512, 0, stream>>>(XWf, XWb, oWhhf, oWhhb, enc, hTf, cTf, hTb, cTb, hx, ecnt);

  gemm64<512,1><<<dim3(256,4), 256, 0, stream>>>(enc, 512, oWaE, 512, attnb, epb, 256);

  init_states<<<64, 256, 0, stream>>>(hTf, hTb, cTf, cTb, c0g, c1g, h0buf, h1buf);

  decoder_kernel<<<128, 512, 0, stream>>>(epb, enc, temb, oWaH, oW0, oW1,
      attnv, d0b, d1b, c0g, c1g, h0buf, h1buf, ctxg, scoreg, dout, dcnt);

  gemm64<256,0><<<dim3(64,500), 256, 0, stream>>>(dout, 256, oprojW, 256, projb, (float*)d_out, 32000);
}

// Round 6
// 4596.235 us; speedup vs baseline: 1.3527x; 1.3527x over previous
//
#include <hip/hip_runtime.h>

// B=64, S=256, T=64, E=256, H=256, G=4H=1024, VT=32000
typedef unsigned short u16;
typedef unsigned int u32;
typedef unsigned long long u64;
typedef short s8v __attribute__((ext_vector_type(8)));
typedef float f32x4 __attribute__((ext_vector_type(4)));
typedef unsigned short us4 __attribute__((ext_vector_type(4)));

#define MFMA16(a,b,c) __builtin_amdgcn_mfma_f32_16x16x32_bf16(a,b,c,0,0,0)

__device__ __forceinline__ float b2f(u16 u){ union{u32 i; float f;} v; v.i=((u32)u)<<16; return v.f; }
__device__ __forceinline__ u16 f2b(float f){ union{float f; u32 i;} v; v.f=f; u32 r=v.i+0x7FFFu+((v.i>>16)&1u); return (u16)(r>>16); }
__device__ __forceinline__ float sigf(float x){ return 1.f/(1.f+__expf(-x)); }
__device__ __forceinline__ float tanh_(float x){ x=fminf(15.f,fmaxf(-15.f,x)); float e=__expf(2.f*x); return (e-1.f)/(e+1.f); }
__device__ __forceinline__ float tanhs(float x){ float e=__expf(2.f*x); return 1.f - 2.f/(e+1.f); }

union FU { s8v v; us4 h[2]; };

// sc1 (coherent, bypass L1/L2) helpers: relaxed agent-scope atomics.
__device__ __forceinline__ us4 ld8_sys(const u16* p){
  u64 v = __hip_atomic_load((const u64*)p, __ATOMIC_RELAXED, __HIP_MEMORY_SCOPE_AGENT);
  union{u64 q; us4 h;} x; x.q=v; return x.h;
}
__device__ __forceinline__ float2 ld8f2(const float* p){
  u64 v = __hip_atomic_load((const u64*)p, __ATOMIC_RELAXED, __HIP_MEMORY_SCOPE_AGENT);
  union{u64 q; float2 f;} x; x.q=v; return x.f;
}
__device__ __forceinline__ void st4_sys(u16* p, u32 v){
  __hip_atomic_store((u32*)p, v, __ATOMIC_RELAXED, __HIP_MEMORY_SCOPE_AGENT);
}
__device__ __forceinline__ void st4f(float* p, float v){
  union{float f; u32 i;} u; u.f=v;
  __hip_atomic_store((u32*)p, u.i, __ATOMIC_RELAXED, __HIP_MEMORY_SCOPE_AGENT);
}
__device__ __forceinline__ void st8_sys(u16* p, us4 v){
  union{us4 h; u64 q;} x; x.h=v;
  __hip_atomic_store((u64*)p, x.q, __ATOMIC_RELAXED, __HIP_MEMORY_SCOPE_AGENT);
}
__device__ __forceinline__ int ldcnt(const int* p){
  return __hip_atomic_load(p, __ATOMIC_RELAXED, __HIP_MEMORY_SCOPE_AGENT);
}
__device__ __forceinline__ void addcnt(int* p){
  __hip_atomic_fetch_add(p, 1, __ATOMIC_RELAXED, __HIP_MEMORY_SCOPE_AGENT);
}

// Fragment loaders; A and B use the same k-bijection so the HW k-layout cancels.
__device__ __forceinline__ s8v gfrag(const u16* rowp, int kbase, int g4){
  FU u; const u16* p = rowp + kbase + 4*g4;
  u.h[0] = *(const us4*)p; u.h[1] = *(const us4*)(p+16);
  return u.v;
}
// LDS frag with 8B-granule XOR swizzle (granule ^= row&7).
__device__ __forceinline__ s8v ldsfrag(const u16* lds, int ldk, int row, int kbase, int g4){
  int sw = row&7;
  int g0 = ((kbase+4*g4)>>2)^sw, g1 = ((kbase+16+4*g4)>>2)^sw;
  FU u;
  u.h[0] = *(const us4*)&lds[row*ldk + (g0<<2)];
  u.h[1] = *(const us4*)&lds[row*ldk + (g1<<2)];
  return u.v;
}

// ---------------- prep: f32 -> bf16 weight conversions / relayouts ----------------
__global__ __launch_bounds__(256) void prep_kernel(
    const float* Wihf, const float* Whhf, const float* Wihb, const float* Whhb,
    const float* d0Wih, const float* d0Whh, const float* d1Wih, const float* d1Whh,
    const float* attnW, const float* projW,
    u16* oWihf, u16* oWhhf, u16* oWihb, u16* oWhhb,
    u16* oW0, u16* oW1, u16* oWaH, u16* oWaE, u16* oprojW){
  long long i = (long long)blockIdx.x*256 + threadIdx.x;
  const long long N1 = 262144;
  if (i < N1){ oWihf[i] = f2b(Wihf[i]); return; } i -= N1;
  if (i < N1){ oWhhf[i] = f2b(Whhf[i]); return; } i -= N1;
  if (i < N1){ oWihb[i] = f2b(Wihb[i]); return; } i -= N1;
  if (i < N1){ oWhhb[i] = f2b(Whhb[i]); return; } i -= N1;
  if (i < 1048576){ // W0cat [1024][1024] = [Wih0(768) | Whh0(256)]
    int g = (int)(i>>10), k = (int)(i&1023);
    float v = (k<768) ? d0Wih[(size_t)g*768+k] : d0Whh[(size_t)g*256 + (k-768)];
    oW0[i] = f2b(v); return;
  } i -= 1048576;
  if (i < 524288){ // W1cat [1024][512] = [Wih1(256) | Whh1(256)]
    int g = (int)(i>>9), k = (int)(i&511);
    float v = (k<256) ? d1Wih[(size_t)g*256+k] : d1Whh[(size_t)g*256 + (k-256)];
    oW1[i] = f2b(v); return;
  } i -= 524288;
  if (i < 65536){ int n=(int)(i>>8), k=(int)(i&255); oWaH[i] = f2b(attnW[(size_t)n*768+k]); return; } i -= 65536;
  if (i < 131072){ int n=(int)(i>>9), k=(int)(i&511); oWaE[i] = f2b(attnW[(size_t)n*768+256+k]); return; } i -= 131072;
  if (i < 8192000){ oprojW[i] = f2b(projW[i]); return; }
}

// ---------------- gather ----------------
__global__ __launch_bounds__(256) void gather_kernel(
    const int* src, const int* tgt, const float* src_emb, const float* tgt_emb,
    u16* xs, u16* temb){
  long long i = (long long)blockIdx.x*256 + threadIdx.x;
  if (i < 4194304){
    int e = (int)(i&255); int sb = (int)(i>>8);
    int s = sb>>6, b = sb&63;
    int idx = src[b*256 + s];
    xs[i] = f2b(src_emb[(size_t)idx*256 + e]);
    return;
  }
  long long j = i - 4194304;
  if (j < 1048576){
    int e = (int)(j&255); int tb = (int)(j>>8);
    int t = tb>>6, b = tb&63;
    int idx = tgt[b*64 + t];
    temb[j] = f2b(tgt_emb[(size_t)idx*256 + e]);
  }
}

// ---------------- 64x64-tile MFMA GEMM: C = A @ B^T + bias ----------------
template<int K, int OBF>
__global__ __launch_bounds__(256) void gemm64(
    const u16* __restrict__ A, int lda, const u16* __restrict__ Bw, int ldb,
    const float* __restrict__ bias, void* Cout, long long ldc){
  __shared__ u16 Alds[64*K];
  int tid = threadIdx.x;
  long long mt = blockIdx.x, nt = blockIdx.y;
  const int Kc8 = K>>3;
  for (int it = tid; it < 64*Kc8; it += 256){
    int row = it / Kc8, seg = it % Kc8;
    const u16* src = A + (size_t)(mt*64+row)*lda + seg*8;
    us4 a0 = *(const us4*)src, a1 = *(const us4*)(src+4);
    int sw = row&7;
    *(us4*)&Alds[row*K + ((((seg*2  ))^sw)<<2)] = a0;
    *(us4*)&Alds[row*K + ((((seg*2+1))^sw)<<2)] = a1;
  }
  __syncthreads();
  int w = tid>>6, lane = tid&63;
  int l15 = lane&15, g4 = lane>>4;
  int arow = w*16 + l15;
  const int NKT = K>>5;
  s8v af[NKT];
  #pragma unroll
  for (int kt=0; kt<NKT; ++kt) af[kt] = ldsfrag(Alds, K, arow, kt*32, g4);
  f32x4 acc[4];
  #pragma unroll
  for (int nti=0; nti<4; ++nti){
    const u16* brow = Bw + (size_t)(nt*64 + nti*16 + l15)*ldb;
    f32x4 a = {0.f,0.f,0.f,0.f};
    #pragma unroll
    for (int kt=0; kt<NKT; ++kt) a = MFMA16(af[kt], gfrag(brow, kt*32, g4), a);
    acc[nti] = a;
  }
  #pragma unroll
  for (int nti=0; nti<4; ++nti)
    #pragma unroll
    for (int r=0; r<4; ++r){
      long long rowg = mt*64 + w*16 + 4*g4 + r;
      long long colg = nt*64 + nti*16 + l15;
      float v = acc[nti][r] + bias[colg];
      if (OBF) ((u16*)Cout)[rowg*ldc + colg] = f2b(v);
      else     ((float*)Cout)[rowg*ldc + colg] = v;
    }
}

// ---------------- encoder v3: 16 WGs in pairs, register Whh slice ----------------
// WG: dir=bid&1, bb=(bid>>1)&3 (16 batches), ch=bid>>3 (128 h-cols). Partner = bid^8.
__global__ __launch_bounds__(512,2) void encoder_kernel(
    const u16* __restrict__ XWf, const u16* __restrict__ XWb,
    const u16* __restrict__ Whhf, const u16* __restrict__ Whhb,
    u16* __restrict__ enc_out, float* hTf, float* cTf, float* hTb, float* cTb,
    u16* hx, int* ecnt){
  int bid = blockIdx.x, tid = threadIdx.x;
  int dir = bid&1, bb=(bid>>1)&3, ch=bid>>3;
  const u16* XW  = dir ? XWb : XWf;
  const u16* Whh = dir ? Whhb : Whhf;
  float* hT = dir ? hTb : hTf; float* cT = dir ? cTb : cTf;
  int w = tid>>6, lane = tid&63, l15=lane&15, g4=lane>>4;
  int bg0 = bb*16;
  s8v bwf[4][8];
  #pragma unroll
  for (int i=0;i<4;++i){
    int t4 = w*4+i, q=t4>>3, jt=t4&7;
    const u16* wr = Whh + (size_t)(q*256 + ch*128 + jt*16 + l15)*256;
    #pragma unroll
    for (int kt=0;kt<8;++kt) bwf[i][kt] = gfrag(wr, kt*32, g4);
  }
  int gb = tid>>5, cl = (tid&31)*4; // gate thread: batch gb, local cols cl..cl+3
  float cst[4]={0.f,0.f,0.f,0.f};
  __shared__ u16 hbuf[16*256];
  __shared__ float gacc[512][17];
  for (int i=tid;i<4096;i+=512) hbuf[i]=0;
  __syncthreads();
  int* myc = &ecnt[bid*32];
  int* pc  = &ecnt[(bid^8)*32];
  u16* myhx = hx + (size_t)bid*2*16*128;
  const u16* phx = hx + (size_t)(bid^8)*2*16*128;
  for (int t=0;t<256;++t){
    int s = dir ? 255-t : t;
    us4 xw4[4];
    const u16* xwr = XW + (((size_t)s*64 + bg0 + gb))*1024 + ch*128 + cl;
    #pragma unroll
    for (int qq=0;qq<4;++qq) xw4[qq] = *(const us4*)(xwr + qq*256);
    s8v af[8];
    #pragma unroll
    for (int kt=0;kt<8;++kt) af[kt] = ldsfrag(hbuf, 256, l15, kt*32, g4);
    #pragma unroll
    for (int i=0;i<4;++i){
      f32x4 a={0.f,0.f,0.f,0.f};
      #pragma unroll
      for (int kt=0;kt<8;++kt) a = MFMA16(af[kt], bwf[i][kt], a);
      int t4=w*4+i, q=t4>>3, jt=t4&7;
      // D mapping: m(batch)=4*g4+r, n(col)=l15. gacc[gate*128+col_local][batch].
      #pragma unroll
      for (int r=0;r<4;++r) gacc[q*128 + jt*16 + l15][4*g4+r] = a[r];
    }
    __syncthreads();
    float hvv[4];
    #pragma unroll
    for (int cc=0;cc<4;++cc){
      int clc = cl+cc;
      float gi = gacc[clc][gb]     + b2f(xw4[0][cc]);
      float gf = gacc[128+clc][gb] + b2f(xw4[1][cc]);
      float gg = gacc[256+clc][gb] + b2f(xw4[2][cc]);
      float go = gacc[384+clc][gb] + b2f(xw4[3][cc]);
      float iv=sigf(gi), fv=sigf(gf), gv=tanh_(gg), ov=sigf(go);
      float cn = fv*cst[cc]+iv*gv; cst[cc]=cn;
      hvv[cc] = ov*tanh_(cn);
    }
    us4 hv4;
    #pragma unroll
    for (int cc=0;cc<4;++cc) hv4[cc] = f2b(hvv[cc]);
    *(us4*)&enc_out[(((size_t)(bg0+gb)*256 + s))*512 + dir*256 + ch*128 + cl] = hv4;
    if (t==255){
      #pragma unroll
      for (int cc=0;cc<4;++cc){
        hT[(bg0+gb)*256 + ch*128 + cl+cc] = hvv[cc];
        cT[(bg0+gb)*256 + ch*128 + cl+cc] = cst[cc];
      }
    } else {
      int col = ch*128 + cl;
      *(us4*)&hbuf[gb*256 + ((((col>>2)) ^ (gb&7))<<2)] = hv4;
      st8_sys(myhx + ((size_t)(t&1)*16*128) + gb*128 + cl, hv4);
      asm volatile("s_waitcnt vmcnt(0)" ::: "memory");
      __syncthreads();
      if (tid==0){
        addcnt(myc);
        while (ldcnt(pc) < t+1) __builtin_amdgcn_s_sleep(1);
      }
      __syncthreads();
      int b2 = tid>>5, cl4 = (tid&31)*4;
      us4 pv = ld8_sys(phx + ((size_t)(t&1)*16*128) + b2*128 + cl4);
      int pcol = (1-ch)*128 + cl4;
      *(us4*)&hbuf[b2*256 + ((((pcol>>2)) ^ (b2&7))<<2)] = pv;
      __syncthreads();
    }
  }
}

// ---------------- init decoder states ----------------
__global__ __launch_bounds__(256) void init_states(
    const float* hTf, const float* hTb, const float* cTf, const float* cTb,
    float* c0g, float* c1g, u16* h0buf, u16* h1buf){
  int i = blockIdx.x*256 + threadIdx.x; // 16384
  float h = hTf[i] + hTb[i];
  float c = cTf[i] + cTb[i];
  c0g[i]=c; c1g[i]=c;
  u16 hb = f2b(h);
  h0buf[16384+i] = hb;  // parity-1 slot (read at tt=0)
  h1buf[16384+i] = hb;
}

// ---------------- decoder v4: 8 groups x 16 WGs; epb in LDS, enc d-slice in VGPRs ----
// group g=bid&7: batches 8g..8g+7. WG c=bid>>3: h-cols 16c..+16, s-slice [16c,16c+16),
// ctx d-slice [32c,32c+32). epb s-slice staged in LDS once; enc d-slice in registers.
__global__ __launch_bounds__(512,2) void decoder_kernel(
    const u16* __restrict__ epb, const u16* __restrict__ enc, const u16* __restrict__ temb,
    const u16* __restrict__ WaH, const u16* __restrict__ W0, const u16* __restrict__ W1,
    const float* __restrict__ attn_v, const float* __restrict__ b0, const float* __restrict__ b1,
    const float* __restrict__ c0init, const float* __restrict__ c1init,
    u16* h0buf, u16* h1buf, u16* ctxg, float* scoreg, u16* dout, int* dcnt){
  int bid = blockIdx.x, tid = threadIdx.x;
  int g = bid&7, c = bid>>3;
  int w = tid>>6, lane = tid&63, l15 = lane&15, g4 = lane>>4;
  int bg0 = g*8;
  int q = w&3, kh = w>>2;
  // register-resident cell weight slices
  s8v b0f[16], b1f[8];
  {
    const u16* w0r = W0 + (size_t)(q*256 + c*16 + l15)*1024 + kh*512;
    const u16* w1r = W1 + (size_t)(q*256 + c*16 + l15)*512  + kh*256;
    #pragma unroll
    for (int kt=0;kt<16;++kt) b0f[kt] = gfrag(w0r, kt*32, g4);
    #pragma unroll
    for (int kt=0;kt<8;++kt)  b1f[kt] = gfrag(w1r, kt*32, g4);
  }
  // enc d-slice in VGPRs: wave w = batch, lane: dp=lane&15 (d-pair), sq=lane>>4 (s-quarter)
  u32 encp[64];
  {
    int dp = lane&15, sq = lane>>4;
    const u16* eb2 = enc + ((size_t)((bg0+w)*256 + sq*64))*512 + c*32 + dp*2;
    #pragma unroll
    for (int sl=0; sl<64; ++sl) encp[sl] = *(const u32*)(eb2 + (size_t)sl*512);
  }
  int cb = tid>>4, ci = tid&15; // gate thread (tid<128): batch cb, col ci
  float c0r=0.f, c1r=0.f, bias0[4], bias1[4];
  if (tid<128){
    c0r = c0init[(bg0+cb)*256 + c*16+ci];
    c1r = c1init[(bg0+cb)*256 + c*16+ci];
    #pragma unroll
    for (int qq=0;qq<4;++qq){ bias0[qq]=b0[qq*256 + c*16+ci]; bias1[qq]=b1[qq*256 + c*16+ci]; }
  }
  // LDS: epb slice [8b][16s] rows, 264-elem rows, k2 chunks at 66-elem stride
  // (bank = 4*sl + k2 + u2 mod 32 -> conflict-free u32 reads)
  __shared__ u16 epl[128*264];
  __shared__ u16 x0l[16*1024];
  __shared__ u16 x1l[16*512];
  __shared__ u16 h1l[16*256];
  __shared__ float qls[8][257];
  __shared__ float scls[8][257];
  __shared__ float red[8][16][17];
  __shared__ float vl[256];
  if (tid<256) vl[tid] = attn_v[tid];
  for (int i=tid;i<8192;i+=512) x0l[8192+i]=0;   // rows 8..15 zero
  for (int i=tid;i<4096;i+=512) x1l[4096+i]=0;
  for (int i=tid;i<2048;i+=512) h1l[2048+i]=0;
  // stage epb s-slice into LDS (once)
  {
    int pr = tid>>2, k2 = tid&3;
    int b2 = pr>>4, sl = pr&15;
    const u16* ep = epb + ((size_t)((bg0+b2)*256 + c*16+sl))*256 + k2*64;
    u16* dst = &epl[(b2*16+sl)*264 + k2*66];
    #pragma unroll
    for (int u2=0; u2<16; ++u2){
      us4 v4 = *(const us4*)(ep + u2*4);
      *(u32*)&dst[u2*4]   = (u32)(u16)v4[0] | ((u32)(u16)v4[1]<<16);
      *(u32*)&dst[u2*4+2] = (u32)(u16)v4[2] | ((u32)(u16)v4[3]<<16);
    }
  }
  __syncthreads();
  int* cnt = &dcnt[g*32];
  int bt = 0;

#define GBAR() do{ bt += 16; \
    asm volatile("s_waitcnt vmcnt(0)" ::: "memory"); \
    __syncthreads(); \
    if (tid==0){ addcnt(cnt); while (ldcnt(cnt) < bt) __builtin_amdgcn_s_sleep(1); } \
    __syncthreads(); }while(0)

  for (int tt=0; tt<64; ++tt){
    int par = tt&1, pp = par^1;
    // ===== Phase A: import h1prev; q = h1 @ WaH^T (MFMA); scores from LDS epb =====
    {
      int b2 = tid>>6, c4 = lane*4;
      us4 hv4 = ld8_sys(h1buf + (size_t)pp*16384 + (bg0+b2)*256 + c4);
      *(us4*)&h1l[b2*256 + ((((c4>>2)) ^ b2)<<2)] = hv4;
      int col = 256 + c4;
      *(us4*)&x1l[b2*512 + ((((col>>2)) ^ b2)<<2)] = hv4;
    }
    __syncthreads();
    #pragma unroll
    for (int t2=0;t2<2;++t2){
      int ct = w*2+t2;
      const u16* br = WaH + (size_t)(ct*16 + l15)*256;
      f32x4 a = {0.f,0.f,0.f,0.f};
      #pragma unroll
      for (int kt=0;kt<8;++kt) a = MFMA16(ldsfrag(h1l,256,l15,kt*32,g4), gfrag(br,kt*32,g4), a);
      #pragma unroll
      for (int r=0;r<4;++r){ int row=4*g4+r; if(row<8) qls[row][ct*16+l15] = a[r]; }
    }
    __syncthreads();
    {
      int pr = tid>>2, k2 = tid&3;
      int b2 = pr>>4, sl = pr&15, s = c*16+sl;
      const u16* base2 = &epl[(b2*16+sl)*264 + k2*66];
      float p = 0.f;
      #pragma unroll 8
      for (int u2=0; u2<32; ++u2){
        u32 e2 = *(const u32*)&base2[u2*2];
        int h = k2*64 + u2*2;
        p += tanhs(b2f((u16)(e2&0xFFFFu)) + qls[b2][h])   * vl[h];
        p += tanhs(b2f((u16)(e2>>16))     + qls[b2][h+1]) * vl[h+1];
      }
      p += __shfl_xor(p,1); p += __shfl_xor(p,2);
      if (k2==0) st4f(scoreg + (size_t)(bg0+b2)*256 + s, p);
    }
    GBAR();
    // ===== Phase B: softmax (redundant, wave-per-batch) + ctx d-slice from VGPRs =====
    #pragma unroll
    for (int k=0;k<2;++k){
      int idx = tid + k*512;
      int b2 = idx>>7, s2 = (idx&127)*2;
      float2 f2 = ld8f2(scoreg + (size_t)(bg0+b2)*256 + s2);
      scls[b2][s2] = f2.x; scls[b2][s2+1] = f2.y;
    }
    __syncthreads();
    {
      int b2 = w;
      float a0=scls[b2][lane*4], a1=scls[b2][lane*4+1], a2=scls[b2][lane*4+2], a3=scls[b2][lane*4+3];
      float m = fmaxf(fmaxf(a0,a1),fmaxf(a2,a3));
      #pragma unroll
      for (int o2=32;o2;o2>>=1) m = fmaxf(m, __shfl_xor(m,o2));
      float e0=__expf(a0-m), e1=__expf(a1-m), e2=__expf(a2-m), e3=__expf(a3-m);
      float sm = e0+e1+e2+e3;
      #pragma unroll
      for (int o2=32;o2;o2>>=1) sm += __shfl_xor(sm,o2);
      float inv = 1.f/sm;
      scls[b2][lane*4]=e0*inv; scls[b2][lane*4+1]=e1*inv; scls[b2][lane*4+2]=e2*inv; scls[b2][lane*4+3]=e3*inv;
    }
    __syncthreads();
    {
      int dp = lane&15, sq = lane>>4, b2 = w;
      float cp0=0.f, cp1=0.f;
      #pragma unroll
      for (int sl=0; sl<64; ++sl){
        float wgt = scls[b2][sq*64+sl];
        u32 e2 = encp[sl];
        cp0 += wgt * b2f((u16)(e2&0xFFFFu));
        cp1 += wgt * b2f((u16)(e2>>16));
      }
      cp0 += __shfl_xor(cp0,16); cp0 += __shfl_xor(cp0,32);
      cp1 += __shfl_xor(cp1,16); cp1 += __shfl_xor(cp1,32);
      if (sq==0){
        u32 pk = (u32)f2b(cp0) | ((u32)f2b(cp1)<<16);
        st4_sys(ctxg + (size_t)(bg0+b2)*512 + c*32 + dp*2, pk);
      }
    }
    GBAR();
    // ===== Phase C: assemble x0 = [emb | ctx | h0prev]; dec0 cell =====
    {
      int b2 = tid>>6, e4 = lane*4;
      us4 tv = *(const us4*)(temb + ((size_t)tt*64 + bg0 + b2)*256 + e4);
      *(us4*)&x0l[b2*1024 + ((((e4>>2)) ^ b2)<<2)] = tv;
    }
    #pragma unroll
    for (int k=0;k<2;++k){
      int idx = tid + k*512;
      int b2 = idx>>7, c4 = (idx&127)*4;
      us4 cv = ld8_sys(ctxg + (size_t)(bg0+b2)*512 + c4);
      int col = 256 + c4;
      *(us4*)&x0l[b2*1024 + ((((col>>2)) ^ b2)<<2)] = cv;
    }
    {
      int b2 = tid>>6, c4 = lane*4;
      us4 hv4 = ld8_sys(h0buf + (size_t)pp*16384 + (bg0+b2)*256 + c4);
      int col = 768 + c4;
      *(us4*)&x0l[b2*1024 + ((((col>>2)) ^ b2)<<2)] = hv4;
    }
    __syncthreads();
    {
      f32x4 a={0.f,0.f,0.f,0.f};
      #pragma unroll
      for (int kt=0;kt<16;++kt)
        a = MFMA16(ldsfrag(x0l,1024,l15,kh*512+kt*32,g4), b0f[kt], a);
      #pragma unroll
      for (int r=0;r<4;++r) red[w][4*g4+r][l15] = a[r];
    }
    __syncthreads();
    if (tid<128){
      float gi = red[0][cb][ci]+red[4][cb][ci]+bias0[0];
      float gf = red[1][cb][ci]+red[5][cb][ci]+bias0[1];
      float gg = red[2][cb][ci]+red[6][cb][ci]+bias0[2];
      float go = red[3][cb][ci]+red[7][cb][ci]+bias0[3];
      float iv=sigf(gi), fv=sigf(gf), gv=tanh_(gg), ov=sigf(go);
      float cn = fv*c0r+iv*gv; c0r=cn;
      float hv = ov*tanh_(cn);
      int me=f2b(hv), ot=__shfl_xor(me,1);
      if ((tid&1)==0) st4_sys(h0buf + (size_t)par*16384 + (bg0+cb)*256 + c*16+ci,
                              ((u32)me&0xFFFFu)|((u32)ot<<16));
    }
    GBAR();
    // ===== Phase D: x1 = [h0 | h1prev]; dec1 cell =====
    {
      int b2 = tid>>6, c4 = lane*4;
      us4 hv4 = ld8_sys(h0buf + (size_t)par*16384 + (bg0+b2)*256 + c4);
      *(us4*)&x1l[b2*512 + ((((c4>>2)) ^ b2)<<2)] = hv4;
    }
    __syncthreads();
    {
      f32x4 a={0.f,0.f,0.f,0.f};
      #pragma unroll
      for (int kt=0;kt<8;++kt)
        a = MFMA16(ldsfrag(x1l,512,l15,kh*256+kt*32,g4), b1f[kt], a);
      #pragma unroll
      for (int r=0;r<4;++r) red[w][4*g4+r][l15] = a[r];
    }
    __syncthreads();
    if (tid<128){
      float gi = red[0][cb][ci]+red[4][cb][ci]+bias1[0];
      float gf = red[1][cb][ci]+red[5][cb][ci]+bias1[1];
      float gg = red[2][cb][ci]+red[6][cb][ci]+bias1[2];
      float go = red[3][cb][ci]+red[7][cb][ci]+bias1[3];
      float iv=sigf(gi), fv=sigf(gf), gv=tanh_(gg), ov=sigf(go);
      float cn = fv*c1r+iv*gv; c1r=cn;
      float hv = ov*tanh_(cn);
      int me=f2b(hv), ot=__shfl_xor(me,1);
      if ((tid&1)==0){
        u32 pk = ((u32)me&0xFFFFu)|((u32)ot<<16);
        st4_sys(h1buf + (size_t)par*16384 + (bg0+cb)*256 + c*16+ci, pk);
        *(u32*)&dout[((size_t)(bg0+cb)*64+tt)*256 + c*16+ci] = pk;
      }
    }
    GBAR();
  }
#undef GBAR
}

// ---------------- host launcher ----------------
extern "C" void kernel_launch(void* const* d_in, const int* in_sizes, int n_in,
                              void* d_out, int out_size, void* d_ws, size_t ws_size,
                              hipStream_t stream){
  const int*   src     = (const int*)  d_in[0];
  const int*   tgt     = (const int*)  d_in[1];
  const float* src_emb = (const float*)d_in[2];
  const float* tgt_emb = (const float*)d_in[3];
  const float* encfWih = (const float*)d_in[4];
  const float* encfWhh = (const float*)d_in[5];
  const float* encfb   = (const float*)d_in[6];
  const float* encbWih = (const float*)d_in[7];
  const float* encbWhh = (const float*)d_in[8];
  const float* encbb   = (const float*)d_in[9];
  const float* d0Wih   = (const float*)d_in[10];
  const float* d0Whh   = (const float*)d_in[11];
  const float* d0b     = (const float*)d_in[12];
  const float* d1Wih   = (const float*)d_in[13];
  const float* d1Whh   = (const float*)d_in[14];
  const float* d1b     = (const float*)d_in[15];
  const float* attnW   = (const float*)d_in[16];
  const float* attnb   = (const float*)d_in[17];
  const float* attnv   = (const float*)d_in[18];
  const float* projW   = (const float*)d_in[19];
  const float* projb   = (const float*)d_in[20];

  char* ws = (char*)d_ws;
  size_t off = 0;
  auto alloc = [&](size_t bytes)->char*{ char* p = ws + off; off += (bytes + 255) & ~(size_t)255; return p; };

  int* dcnt     = (int*)alloc(1024);
  int* ecnt     = (int*)alloc(2048);
  u16* xs       = (u16*)alloc(16384ULL*256*2);
  u16* temb     = (u16*)alloc(4096ULL*256*2);
  u16* oWihf    = (u16*)alloc(262144ULL*2);
  u16* oWhhf    = (u16*)alloc(262144ULL*2);
  u16* oWihb    = (u16*)alloc(262144ULL*2);
  u16* oWhhb    = (u16*)alloc(262144ULL*2);
  u16* oW0      = (u16*)alloc(1048576ULL*2);
  u16* oW1      = (u16*)alloc(524288ULL*2);
  u16* oWaH     = (u16*)alloc(65536ULL*2);
  u16* oWaE     = (u16*)alloc(131072ULL*2);
  u16* oprojW   = (u16*)alloc(8192000ULL*2);
  u16* XWf      = (u16*)alloc(16384ULL*1024*2);
  u16* XWb      = (u16*)alloc(16384ULL*1024*2);
  u16* enc      = (u16*)alloc(64ULL*256*512*2);
  u16* epb      = (u16*)alloc(64ULL*256*256*2);
  float* hTf    = (float*)alloc(16384ULL*4);
  float* cTf    = (float*)alloc(16384ULL*4);
  float* hTb    = (float*)alloc(16384ULL*4);
  float* cTb    = (float*)alloc(16384ULL*4);
  float* c0g    = (float*)alloc(16384ULL*4);
  float* c1g    = (float*)alloc(16384ULL*4);
  u16* h0buf    = (u16*)alloc(2ULL*16384*2);
  u16* h1buf    = (u16*)alloc(2ULL*16384*2);
  u16* ctxg     = (u16*)alloc(64ULL*512*2);
  float* scoreg = (float*)alloc(16384ULL*4);
  u16* hx       = (u16*)alloc(16ULL*2*16*128*2);
  u16* dout     = (u16*)alloc(4096ULL*256*2);
  if (off > ws_size) return;

  hipMemsetAsync(dcnt, 0, 1024, stream);
  hipMemsetAsync(ecnt, 0, 2048, stream);

  prep_kernel<<<43008, 256, 0, stream>>>(encfWih, encfWhh, encbWih, encbWhh,
      d0Wih, d0Whh, d1Wih, d1Whh, attnW, projW,
      oWihf, oWhhf, oWihb, oWhhb, oW0, oW1, oWaH, oWaE, oprojW);

  gather_kernel<<<20480, 256, 0, stream>>>(src, tgt, src_emb, tgt_emb, xs, temb);

  gemm64<256,1><<<dim3(256,16), 256, 0, stream>>>(xs, 256, oWihf, 256, encfb, XWf, 1024);
  gemm64<256,1><<<dim3(256,16), 256, 0, stream>>>(xs, 256, oWihb, 256, encbb, XWb, 1024);

  encoder_kernel<<<16, 512, 0, stream>>>(XWf, XWb, oWhhf, oWhhb, enc, hTf, cTf, hTb, cTb, hx, ecnt);

  gemm64<512,1><<<dim3(256,4), 256, 0, stream>>>(enc, 512, oWaE, 512, attnb, epb, 256);

  init_states<<<64, 256, 0, stream>>>(hTf, hTb, cTf, cTb, c0g, c1g, h0buf, h1buf);

  decoder_kernel<<<128, 512, 0, stream>>>(epb, enc, temb, oWaH, oW0, oW1,
      attnv, d0b, d1b, c0g, c1g, h0buf, h1buf, ctxg, scoreg, dout, dcnt);

  gemm64<256,0><<<dim3(64,500), 256, 0, stream>>>(dout, 256, oprojW, 256, projb, (float*)d_out, 32000);
}

// Round 7
// 4593.578 us; speedup vs baseline: 1.3535x; 1.0006x over previous
//
#include <hip/hip_runtime.h>

// B=64, S=256, T=64, E=256, H=256, G=4H=1024, VT=32000
typedef unsigned short u16;
typedef unsigned int u32;
typedef unsigned long long u64;
typedef short s8v __attribute__((ext_vector_type(8)));
typedef float f32x4 __attribute__((ext_vector_type(4)));
typedef unsigned short us4 __attribute__((ext_vector_type(4)));

#define MFMA16(a,b,c) __builtin_amdgcn_mfma_f32_16x16x32_bf16(a,b,c,0,0,0)

__device__ __forceinline__ float b2f(u16 u){ union{u32 i; float f;} v; v.i=((u32)u)<<16; return v.f; }
__device__ __forceinline__ u16 f2b(float f){ union{float f; u32 i;} v; v.f=f; u32 r=v.i+0x7FFFu+((v.i>>16)&1u); return (u16)(r>>16); }
__device__ __forceinline__ float sigf(float x){ return 1.f/(1.f+__expf(-x)); }
__device__ __forceinline__ float tanh_(float x){ x=fminf(15.f,fmaxf(-15.f,x)); float e=__expf(2.f*x); return (e-1.f)/(e+1.f); }
__device__ __forceinline__ float tanhs(float x){ float e=__expf(2.f*x); return 1.f - 2.f/(e+1.f); }

union FU { s8v v; us4 h[2]; };

// sc1 (coherent, bypass L1/L2) helpers: relaxed agent-scope atomics.
__device__ __forceinline__ us4 ld8_sys(const u16* p){
  u64 v = __hip_atomic_load((const u64*)p, __ATOMIC_RELAXED, __HIP_MEMORY_SCOPE_AGENT);
  union{u64 q; us4 h;} x; x.q=v; return x.h;
}
__device__ __forceinline__ float2 ld8f2(const float* p){
  u64 v = __hip_atomic_load((const u64*)p, __ATOMIC_RELAXED, __HIP_MEMORY_SCOPE_AGENT);
  union{u64 q; float2 f;} x; x.q=v; return x.f;
}
__device__ __forceinline__ void st4_sys(u16* p, u32 v){
  __hip_atomic_store((u32*)p, v, __ATOMIC_RELAXED, __HIP_MEMORY_SCOPE_AGENT);
}
__device__ __forceinline__ void st4f(float* p, float v){
  union{float f; u32 i;} u; u.f=v;
  __hip_atomic_store((u32*)p, u.i, __ATOMIC_RELAXED, __HIP_MEMORY_SCOPE_AGENT);
}
__device__ __forceinline__ void st8_sys(u16* p, us4 v){
  union{us4 h; u64 q;} x; x.h=v;
  __hip_atomic_store((u64*)p, x.q, __ATOMIC_RELAXED, __HIP_MEMORY_SCOPE_AGENT);
}
__device__ __forceinline__ int ldcnt(const int* p){
  return __hip_atomic_load(p, __ATOMIC_RELAXED, __HIP_MEMORY_SCOPE_AGENT);
}
__device__ __forceinline__ void addcnt(int* p){
  __hip_atomic_fetch_add(p, 1, __ATOMIC_RELAXED, __HIP_MEMORY_SCOPE_AGENT);
}

// Fragment loaders; A and B use the same k-bijection so the HW k-layout cancels.
__device__ __forceinline__ s8v gfrag(const u16* rowp, int kbase, int g4){
  FU u; const u16* p = rowp + kbase + 4*g4;
  u.h[0] = *(const us4*)p; u.h[1] = *(const us4*)(p+16);
  return u.v;
}
// LDS frag with 8B-granule XOR swizzle (granule ^= row&7).
__device__ __forceinline__ s8v ldsfrag(const u16* lds, int ldk, int row, int kbase, int g4){
  int sw = row&7;
  int g0 = ((kbase+4*g4)>>2)^sw, g1 = ((kbase+16+4*g4)>>2)^sw;
  FU u;
  u.h[0] = *(const us4*)&lds[row*ldk + (g0<<2)];
  u.h[1] = *(const us4*)&lds[row*ldk + (g1<<2)];
  return u.v;
}

// ---------------- prep: f32 -> bf16 weight conversions / relayouts ----------------
__global__ __launch_bounds__(256) void prep_kernel(
    const float* Wihf, const float* Whhf, const float* Wihb, const float* Whhb,
    const float* d0Wih, const float* d0Whh, const float* d1Wih, const float* d1Whh,
    const float* attnW, const float* projW,
    u16* oWihf, u16* oWhhf, u16* oWihb, u16* oWhhb,
    u16* oW0, u16* oW1, u16* oWaH, u16* oWaE, u16* oprojW){
  long long i = (long long)blockIdx.x*256 + threadIdx.x;
  const long long N1 = 262144;
  if (i < N1){ oWihf[i] = f2b(Wihf[i]); return; } i -= N1;
  if (i < N1){ oWhhf[i] = f2b(Whhf[i]); return; } i -= N1;
  if (i < N1){ oWihb[i] = f2b(Wihb[i]); return; } i -= N1;
  if (i < N1){ oWhhb[i] = f2b(Whhb[i]); return; } i -= N1;
  if (i < 1048576){ // W0cat [1024][1024] = [Wih0(768) | Whh0(256)]
    int g = (int)(i>>10), k = (int)(i&1023);
    float v = (k<768) ? d0Wih[(size_t)g*768+k] : d0Whh[(size_t)g*256 + (k-768)];
    oW0[i] = f2b(v); return;
  } i -= 1048576;
  if (i < 524288){ // W1cat [1024][512] = [Wih1(256) | Whh1(256)]
    int g = (int)(i>>9), k = (int)(i&511);
    float v = (k<256) ? d1Wih[(size_t)g*256+k] : d1Whh[(size_t)g*256 + (k-256)];
    oW1[i] = f2b(v); return;
  } i -= 524288;
  if (i < 65536){ int n=(int)(i>>8), k=(int)(i&255); oWaH[i] = f2b(attnW[(size_t)n*768+k]); return; } i -= 65536;
  if (i < 131072){ int n=(int)(i>>9), k=(int)(i&511); oWaE[i] = f2b(attnW[(size_t)n*768+256+k]); return; } i -= 131072;
  if (i < 8192000){ oprojW[i] = f2b(projW[i]); return; }
}

// ---------------- gather ----------------
__global__ __launch_bounds__(256) void gather_kernel(
    const int* src, const int* tgt, const float* src_emb, const float* tgt_emb,
    u16* xs, u16* temb){
  long long i = (long long)blockIdx.x*256 + threadIdx.x;
  if (i < 4194304){
    int e = (int)(i&255); int sb = (int)(i>>8);
    int s = sb>>6, b = sb&63;
    int idx = src[b*256 + s];
    xs[i] = f2b(src_emb[(size_t)idx*256 + e]);
    return;
  }
  long long j = i - 4194304;
  if (j < 1048576){
    int e = (int)(j&255); int tb = (int)(j>>8);
    int t = tb>>6, b = tb&63;
    int idx = tgt[b*64 + t];
    temb[j] = f2b(tgt_emb[(size_t)idx*256 + e]);
  }
}

// ---------------- 64x64-tile MFMA GEMM: C = A @ B^T + bias ----------------
template<int K, int OBF>
__global__ __launch_bounds__(256) void gemm64(
    const u16* __restrict__ A, int lda, const u16* __restrict__ Bw, int ldb,
    const float* __restrict__ bias, void* Cout, long long ldc){
  __shared__ u16 Alds[64*K];
  int tid = threadIdx.x;
  long long mt = blockIdx.x, nt = blockIdx.y;
  const int Kc8 = K>>3;
  for (int it = tid; it < 64*Kc8; it += 256){
    int row = it / Kc8, seg = it % Kc8;
    const u16* src = A + (size_t)(mt*64+row)*lda + seg*8;
    us4 a0 = *(const us4*)src, a1 = *(const us4*)(src+4);
    int sw = row&7;
    *(us4*)&Alds[row*K + ((((seg*2  ))^sw)<<2)] = a0;
    *(us4*)&Alds[row*K + ((((seg*2+1))^sw)<<2)] = a1;
  }
  __syncthreads();
  int w = tid>>6, lane = tid&63;
  int l15 = lane&15, g4 = lane>>4;
  int arow = w*16 + l15;
  const int NKT = K>>5;
  s8v af[NKT];
  #pragma unroll
  for (int kt=0; kt<NKT; ++kt) af[kt] = ldsfrag(Alds, K, arow, kt*32, g4);
  f32x4 acc[4];
  #pragma unroll
  for (int nti=0; nti<4; ++nti){
    const u16* brow = Bw + (size_t)(nt*64 + nti*16 + l15)*ldb;
    f32x4 a = {0.f,0.f,0.f,0.f};
    #pragma unroll
    for (int kt=0; kt<NKT; ++kt) a = MFMA16(af[kt], gfrag(brow, kt*32, g4), a);
    acc[nti] = a;
  }
  #pragma unroll
  for (int nti=0; nti<4; ++nti)
    #pragma unroll
    for (int r=0; r<4; ++r){
      long long rowg = mt*64 + w*16 + 4*g4 + r;
      long long colg = nt*64 + nti*16 + l15;
      float v = acc[nti][r] + bias[colg];
      if (OBF) ((u16*)Cout)[rowg*ldc + colg] = f2b(v);
      else     ((float*)Cout)[rowg*ldc + colg] = v;
    }
}

// ---------------- encoder v3: 16 WGs in pairs, register Whh slice ----------------
// WG: dir=bid&1, bb=(bid>>1)&3 (16 batches), ch=bid>>3 (128 h-cols). Partner = bid^8.
__global__ __launch_bounds__(512,2) void encoder_kernel(
    const u16* __restrict__ XWf, const u16* __restrict__ XWb,
    const u16* __restrict__ Whhf, const u16* __restrict__ Whhb,
    u16* __restrict__ enc_out, float* hTf, float* cTf, float* hTb, float* cTb,
    u16* hx, int* ecnt){
  int bid = blockIdx.x, tid = threadIdx.x;
  int dir = bid&1, bb=(bid>>1)&3, ch=bid>>3;
  const u16* XW  = dir ? XWb : XWf;
  const u16* Whh = dir ? Whhb : Whhf;
  float* hT = dir ? hTb : hTf; float* cT = dir ? cTb : cTf;
  int w = tid>>6, lane = tid&63, l15=lane&15, g4=lane>>4;
  int bg0 = bb*16;
  s8v bwf[4][8];
  #pragma unroll
  for (int i=0;i<4;++i){
    int t4 = w*4+i, q=t4>>3, jt=t4&7;
    const u16* wr = Whh + (size_t)(q*256 + ch*128 + jt*16 + l15)*256;
    #pragma unroll
    for (int kt=0;kt<8;++kt) bwf[i][kt] = gfrag(wr, kt*32, g4);
  }
  int gb = tid>>5, cl = (tid&31)*4; // gate thread: batch gb, local cols cl..cl+3
  float cst[4]={0.f,0.f,0.f,0.f};
  __shared__ u16 hbuf[16*256];
  __shared__ float gacc[512][17];
  for (int i=tid;i<4096;i+=512) hbuf[i]=0;
  __syncthreads();
  int* myc = &ecnt[bid*32];
  int* pc  = &ecnt[(bid^8)*32];
  u16* myhx = hx + (size_t)bid*2*16*128;
  const u16* phx = hx + (size_t)(bid^8)*2*16*128;
  for (int t=0;t<256;++t){
    int s = dir ? 255-t : t;
    us4 xw4[4];
    const u16* xwr = XW + (((size_t)s*64 + bg0 + gb))*1024 + ch*128 + cl;
    #pragma unroll
    for (int qq=0;qq<4;++qq) xw4[qq] = *(const us4*)(xwr + qq*256);
    s8v af[8];
    #pragma unroll
    for (int kt=0;kt<8;++kt) af[kt] = ldsfrag(hbuf, 256, l15, kt*32, g4);
    #pragma unroll
    for (int i=0;i<4;++i){
      f32x4 a={0.f,0.f,0.f,0.f};
      #pragma unroll
      for (int kt=0;kt<8;++kt) a = MFMA16(af[kt], bwf[i][kt], a);
      int t4=w*4+i, q=t4>>3, jt=t4&7;
      // D mapping: m(batch)=4*g4+r, n(col)=l15. gacc[gate*128+col_local][batch].
      #pragma unroll
      for (int r=0;r<4;++r) gacc[q*128 + jt*16 + l15][4*g4+r] = a[r];
    }
    __syncthreads();
    float hvv[4];
    #pragma unroll
    for (int cc=0;cc<4;++cc){
      int clc = cl+cc;
      float gi = gacc[clc][gb]     + b2f(xw4[0][cc]);
      float gf = gacc[128+clc][gb] + b2f(xw4[1][cc]);
      float gg = gacc[256+clc][gb] + b2f(xw4[2][cc]);
      float go = gacc[384+clc][gb] + b2f(xw4[3][cc]);
      float iv=sigf(gi), fv=sigf(gf), gv=tanh_(gg), ov=sigf(go);
      float cn = fv*cst[cc]+iv*gv; cst[cc]=cn;
      hvv[cc] = ov*tanh_(cn);
    }
    us4 hv4;
    #pragma unroll
    for (int cc=0;cc<4;++cc) hv4[cc] = f2b(hvv[cc]);
    *(us4*)&enc_out[(((size_t)(bg0+gb)*256 + s))*512 + dir*256 + ch*128 + cl] = hv4;
    if (t==255){
      #pragma unroll
      for (int cc=0;cc<4;++cc){
        hT[(bg0+gb)*256 + ch*128 + cl+cc] = hvv[cc];
        cT[(bg0+gb)*256 + ch*128 + cl+cc] = cst[cc];
      }
    } else {
      int col = ch*128 + cl;
      *(us4*)&hbuf[gb*256 + ((((col>>2)) ^ (gb&7))<<2)] = hv4;
      st8_sys(myhx + ((size_t)(t&1)*16*128) + gb*128 + cl, hv4);
      asm volatile("s_waitcnt vmcnt(0)" ::: "memory");
      __syncthreads();
      if (tid==0){
        addcnt(myc);
        while (ldcnt(pc) < t+1) __builtin_amdgcn_s_sleep(1);
      }
      __syncthreads();
      int b2 = tid>>5, cl4 = (tid&31)*4;
      us4 pv = ld8_sys(phx + ((size_t)(t&1)*16*128) + b2*128 + cl4);
      int pcol = (1-ch)*128 + cl4;
      *(us4*)&hbuf[b2*256 + ((((pcol>>2)) ^ (b2&7))<<2)] = pv;
      __syncthreads();
    }
  }
}

// ---------------- init decoder states ----------------
__global__ __launch_bounds__(256) void init_states(
    const float* hTf, const float* hTb, const float* cTf, const float* cTb,
    float* c0g, float* c1g, u16* h0buf, u16* h1buf){
  int i = blockIdx.x*256 + threadIdx.x; // 16384
  float h = hTf[i] + hTb[i];
  float c = cTf[i] + cTb[i];
  c0g[i]=c; c1g[i]=c;
  u16 hb = f2b(h);
  h0buf[16384+i] = hb;  // parity-1 slot (read at tt=0)
  h1buf[16384+i] = hb;
}

// ---------------- decoder v4.1: 8 groups x 16 WGs; epb in LDS, enc d-slice in VGPRs ----
// group g=bid&7: batches 8g..8g+7. WG c=bid>>3: h-cols 16c..+16, s-slice [16c,16c+16),
// ctx d-slice [32c,32c+32). epb s-slice staged in LDS once; enc d-slice in registers.
// launch_bounds(512,1): LDS (148KB) already caps at 1 WG/CU; (512,2) capped VGPRs at 128
// and spilled encp[64]+weight frags to scratch -> 1.5GB/dispatch global traffic (R6 PMC).
__global__ __launch_bounds__(512,1) void decoder_kernel(
    const u16* __restrict__ epb, const u16* __restrict__ enc, const u16* __restrict__ temb,
    const u16* __restrict__ WaH, const u16* __restrict__ W0, const u16* __restrict__ W1,
    const float* __restrict__ attn_v, const float* __restrict__ b0, const float* __restrict__ b1,
    const float* __restrict__ c0init, const float* __restrict__ c1init,
    u16* h0buf, u16* h1buf, u16* ctxg, float* scoreg, u16* dout, int* dcnt){
  int bid = blockIdx.x, tid = threadIdx.x;
  int g = bid&7, c = bid>>3;
  int w = tid>>6, lane = tid&63, l15 = lane&15, g4 = lane>>4;
  int bg0 = g*8;
  int q = w&3, kh = w>>2;
  // register-resident cell weight slices
  s8v b0f[16], b1f[8];
  {
    const u16* w0r = W0 + (size_t)(q*256 + c*16 + l15)*1024 + kh*512;
    const u16* w1r = W1 + (size_t)(q*256 + c*16 + l15)*512  + kh*256;
    #pragma unroll
    for (int kt=0;kt<16;++kt) b0f[kt] = gfrag(w0r, kt*32, g4);
    #pragma unroll
    for (int kt=0;kt<8;++kt)  b1f[kt] = gfrag(w1r, kt*32, g4);
  }
  // enc d-slice in VGPRs: wave w = batch, lane: dp=lane&15 (d-pair), sq=lane>>4 (s-quarter)
  u32 encp[64];
  {
    int dp = lane&15, sq = lane>>4;
    const u16* eb2 = enc + ((size_t)((bg0+w)*256 + sq*64))*512 + c*32 + dp*2;
    #pragma unroll
    for (int sl=0; sl<64; ++sl) encp[sl] = *(const u32*)(eb2 + (size_t)sl*512);
  }
  int cb = tid>>4, ci = tid&15; // gate thread (tid<128): batch cb, col ci
  float c0r=0.f, c1r=0.f, bias0[4], bias1[4];
  if (tid<128){
    c0r = c0init[(bg0+cb)*256 + c*16+ci];
    c1r = c1init[(bg0+cb)*256 + c*16+ci];
    #pragma unroll
    for (int qq=0;qq<4;++qq){ bias0[qq]=b0[qq*256 + c*16+ci]; bias1[qq]=b1[qq*256 + c*16+ci]; }
  }
  // LDS: epb slice [8b][16s] rows, 264-elem rows, k2 chunks at 66-elem stride
  __shared__ u16 epl[128*264];
  __shared__ u16 x0l[16*1024];
  __shared__ u16 x1l[16*512];
  __shared__ u16 h1l[16*256];
  __shared__ float qls[8][257];
  __shared__ float scls[8][257];
  __shared__ float red[8][16][17];
  __shared__ float vl[256];
  if (tid<256) vl[tid] = attn_v[tid];
  for (int i=tid;i<8192;i+=512) x0l[8192+i]=0;   // rows 8..15 zero
  for (int i=tid;i<4096;i+=512) x1l[4096+i]=0;
  for (int i=tid;i<2048;i+=512) h1l[2048+i]=0;
  // stage epb s-slice into LDS (once)
  {
    int pr = tid>>2, k2 = tid&3;
    int b2 = pr>>4, sl = pr&15;
    const u16* ep = epb + ((size_t)((bg0+b2)*256 + c*16+sl))*256 + k2*64;
    u16* dst = &epl[(b2*16+sl)*264 + k2*66];
    #pragma unroll
    for (int u2=0; u2<16; ++u2){
      us4 v4 = *(const us4*)(ep + u2*4);
      *(u32*)&dst[u2*4]   = (u32)(u16)v4[0] | ((u32)(u16)v4[1]<<16);
      *(u32*)&dst[u2*4+2] = (u32)(u16)v4[2] | ((u32)(u16)v4[3]<<16);
    }
  }
  __syncthreads();
  int* cnt = &dcnt[g*32];
  int bt = 0;

#define GBAR() do{ bt += 16; \
    asm volatile("s_waitcnt vmcnt(0)" ::: "memory"); \
    __syncthreads(); \
    if (tid==0){ addcnt(cnt); while (ldcnt(cnt) < bt) __builtin_amdgcn_s_sleep(1); } \
    __syncthreads(); }while(0)

  for (int tt=0; tt<64; ++tt){
    int par = tt&1, pp = par^1;
    // ===== Phase A: import h1prev; q = h1 @ WaH^T (MFMA); scores from LDS epb =====
    {
      int b2 = tid>>6, c4 = lane*4;
      us4 hv4 = ld8_sys(h1buf + (size_t)pp*16384 + (bg0+b2)*256 + c4);
      *(us4*)&h1l[b2*256 + ((((c4>>2)) ^ b2)<<2)] = hv4;
      int col = 256 + c4;
      *(us4*)&x1l[b2*512 + ((((col>>2)) ^ b2)<<2)] = hv4;
    }
    __syncthreads();
    #pragma unroll
    for (int t2=0;t2<2;++t2){
      int ct = w*2+t2;
      const u16* br = WaH + (size_t)(ct*16 + l15)*256;
      f32x4 a = {0.f,0.f,0.f,0.f};
      #pragma unroll
      for (int kt=0;kt<8;++kt) a = MFMA16(ldsfrag(h1l,256,l15,kt*32,g4), gfrag(br,kt*32,g4), a);
      #pragma unroll
      for (int r=0;r<4;++r){ int row=4*g4+r; if(row<8) qls[row][ct*16+l15] = a[r]; }
    }
    __syncthreads();
    {
      int pr = tid>>2, k2 = tid&3;
      int b2 = pr>>4, sl = pr&15, s = c*16+sl;
      const u16* base2 = &epl[(b2*16+sl)*264 + k2*66];
      float p = 0.f;
      #pragma unroll 8
      for (int u2=0; u2<32; ++u2){
        u32 e2 = *(const u32*)&base2[u2*2];
        int h = k2*64 + u2*2;
        p += tanhs(b2f((u16)(e2&0xFFFFu)) + qls[b2][h])   * vl[h];
        p += tanhs(b2f((u16)(e2>>16))     + qls[b2][h+1]) * vl[h+1];
      }
      p += __shfl_xor(p,1); p += __shfl_xor(p,2);
      if (k2==0) st4f(scoreg + (size_t)(bg0+b2)*256 + s, p);
    }
    GBAR();
    // ===== Phase B: softmax (redundant, wave-per-batch) + ctx d-slice from VGPRs =====
    #pragma unroll
    for (int k=0;k<2;++k){
      int idx = tid + k*512;
      int b2 = idx>>7, s2 = (idx&127)*2;
      float2 f2 = ld8f2(scoreg + (size_t)(bg0+b2)*256 + s2);
      scls[b2][s2] = f2.x; scls[b2][s2+1] = f2.y;
    }
    __syncthreads();
    {
      int b2 = w;
      float a0=scls[b2][lane*4], a1=scls[b2][lane*4+1], a2=scls[b2][lane*4+2], a3=scls[b2][lane*4+3];
      float m = fmaxf(fmaxf(a0,a1),fmaxf(a2,a3));
      #pragma unroll
      for (int o2=32;o2;o2>>=1) m = fmaxf(m, __shfl_xor(m,o2));
      float e0=__expf(a0-m), e1=__expf(a1-m), e2=__expf(a2-m), e3=__expf(a3-m);
      float sm = e0+e1+e2+e3;
      #pragma unroll
      for (int o2=32;o2;o2>>=1) sm += __shfl_xor(sm,o2);
      float inv = 1.f/sm;
      scls[b2][lane*4]=e0*inv; scls[b2][lane*4+1]=e1*inv; scls[b2][lane*4+2]=e2*inv; scls[b2][lane*4+3]=e3*inv;
    }
    __syncthreads();
    {
      int dp = lane&15, sq = lane>>4, b2 = w;
      float cp0=0.f, cp1=0.f;
      #pragma unroll
      for (int sl=0; sl<64; ++sl){
        float wgt = scls[b2][sq*64+sl];
        u32 e2 = encp[sl];
        cp0 += wgt * b2f((u16)(e2&0xFFFFu));
        cp1 += wgt * b2f((u16)(e2>>16));
      }
      cp0 += __shfl_xor(cp0,16); cp0 += __shfl_xor(cp0,32);
      cp1 += __shfl_xor(cp1,16); cp1 += __shfl_xor(cp1,32);
      if (sq==0){
        u32 pk = (u32)f2b(cp0) | ((u32)f2b(cp1)<<16);
        st4_sys(ctxg + (size_t)(bg0+b2)*512 + c*32 + dp*2, pk);
      }
    }
    GBAR();
    // ===== Phase C: assemble x0 = [emb | ctx | h0prev]; dec0 cell =====
    {
      int b2 = tid>>6, e4 = lane*4;
      us4 tv = *(const us4*)(temb + ((size_t)tt*64 + bg0 + b2)*256 + e4);
      *(us4*)&x0l[b2*1024 + ((((e4>>2)) ^ b2)<<2)] = tv;
    }
    #pragma unroll
    for (int k=0;k<2;++k){
      int idx = tid + k*512;
      int b2 = idx>>7, c4 = (idx&127)*4;
      us4 cv = ld8_sys(ctxg + (size_t)(bg0+b2)*512 + c4);
      int col = 256 + c4;
      *(us4*)&x0l[b2*1024 + ((((col>>2)) ^ b2)<<2)] = cv;
    }
    {
      int b2 = tid>>6, c4 = lane*4;
      us4 hv4 = ld8_sys(h0buf + (size_t)pp*16384 + (bg0+b2)*256 + c4);
      int col = 768 + c4;
      *(us4*)&x0l[b2*1024 + ((((col>>2)) ^ b2)<<2)] = hv4;
    }
    __syncthreads();
    {
      f32x4 a={0.f,0.f,0.f,0.f};
      #pragma unroll
      for (int kt=0;kt<16;++kt)
        a = MFMA16(ldsfrag(x0l,1024,l15,kh*512+kt*32,g4), b0f[kt], a);
      #pragma unroll
      for (int r=0;r<4;++r) red[w][4*g4+r][l15] = a[r];
    }
    __syncthreads();
    if (tid<128){
      float gi = red[0][cb][ci]+red[4][cb][ci]+bias0[0];
      float gf = red[1][cb][ci]+red[5][cb][ci]+bias0[1];
      float gg = red[2][cb][ci]+red[6][cb][ci]+bias0[2];
      float go = red[3][cb][ci]+red[7][cb][ci]+bias0[3];
      float iv=sigf(gi), fv=sigf(gf), gv=tanh_(gg), ov=sigf(go);
      float cn = fv*c0r+iv*gv; c0r=cn;
      float hv = ov*tanh_(cn);
      int me=f2b(hv), ot=__shfl_xor(me,1);
      if ((tid&1)==0) st4_sys(h0buf + (size_t)par*16384 + (bg0+cb)*256 + c*16+ci,
                              ((u32)me&0xFFFFu)|((u32)ot<<16));
    }
    GBAR();
    // ===== Phase D: x1 = [h0 | h1prev]; dec1 cell =====
    {
      int b2 = tid>>6, c4 = lane*4;
      us4 hv4 = ld8_sys(h0buf + (size_t)par*16384 + (bg0+b2)*256 + c4);
      *(us4*)&x1l[b2*512 + ((((c4>>2)) ^ b2)<<2)] = hv4;
    }
    __syncthreads();
    {
      f32x4 a={0.f,0.f,0.f,0.f};
      #pragma unroll
      for (int kt=0;kt<8;++kt)
        a = MFMA16(ldsfrag(x1l,512,l15,kh*256+kt*32,g4), b1f[kt], a);
      #pragma unroll
      for (int r=0;r<4;++r) red[w][4*g4+r][l15] = a[r];
    }
    __syncthreads();
    if (tid<128){
      float gi = red[0][cb][ci]+red[4][cb][ci]+bias1[0];
      float gf = red[1][cb][ci]+red[5][cb][ci]+bias1[1];
      float gg = red[2][cb][ci]+red[6][cb][ci]+bias1[2];
      float go = red[3][cb][ci]+red[7][cb][ci]+bias1[3];
      float iv=sigf(gi), fv=sigf(gf), gv=tanh_(gg), ov=sigf(go);
      float cn = fv*c1r+iv*gv; c1r=cn;
      float hv = ov*tanh_(cn);
      int me=f2b(hv), ot=__shfl_xor(me,1);
      if ((tid&1)==0){
        u32 pk = ((u32)me&0xFFFFu)|((u32)ot<<16);
        st4_sys(h1buf + (size_t)par*16384 + (bg0+cb)*256 + c*16+ci, pk);
        *(u32*)&dout[((size_t)(bg0+cb)*64+tt)*256 + c*16+ci] = pk;
      }
    }
    GBAR();
  }
#undef GBAR
}

// ---------------- host launcher ----------------
extern "C" void kernel_launch(void* const* d_in, const int* in_sizes, int n_in,
                              void* d_out, int out_size, void* d_ws, size_t ws_size,
                              hipStream_t stream){
  const int*   src     = (const int*)  d_in[0];
  const int*   tgt     = (const int*)  d_in[1];
  const float* src_emb = (const float*)d_in[2];
  const float* tgt_emb = (const float*)d_in[3];
  const float* encfWih = (const float*)d_in[4];
  const float* encfWhh = (const float*)d_in[5];
  const float* encfb   = (const float*)d_in[6];
  const float* encbWih = (const float*)d_in[7];
  const float* encbWhh = (const float*)d_in[8];
  const float* encbb   = (const float*)d_in[9];
  const float* d0Wih   = (const float*)d_in[10];
  const float* d0Whh   = (const float*)d_in[11];
  const float* d0b     = (const float*)d_in[12];
  const float* d1Wih   = (const float*)d_in[13];
  const float* d1Whh   = (const float*)d_in[14];
  const float* d1b     = (const float*)d_in[15];
  const float* attnW   = (const float*)d_in[16];
  const float* attnb   = (const float*)d_in[17];
  const float* attnv   = (const float*)d_in[18];
  const float* projW   = (const float*)d_in[19];
  const float* projb   = (const float*)d_in[20];

  char* ws = (char*)d_ws;
  size_t off = 0;
  auto alloc = [&](size_t bytes)->char*{ char* p = ws + off; off += (bytes + 255) & ~(size_t)255; return p; };

  int* dcnt     = (int*)alloc(1024);
  int* ecnt     = (int*)alloc(2048);
  u16* xs       = (u16*)alloc(16384ULL*256*2);
  u16* temb     = (u16*)alloc(4096ULL*256*2);
  u16* oWihf    = (u16*)alloc(262144ULL*2);
  u16* oWhhf    = (u16*)alloc(262144ULL*2);
  u16* oWihb    = (u16*)alloc(262144ULL*2);
  u16* oWhhb    = (u16*)alloc(262144ULL*2);
  u16* oW0      = (u16*)alloc(1048576ULL*2);
  u16* oW1      = (u16*)alloc(524288ULL*2);
  u16* oWaH     = (u16*)alloc(65536ULL*2);
  u16* oWaE     = (u16*)alloc(131072ULL*2);
  u16* oprojW   = (u16*)alloc(8192000ULL*2);
  u16* XWf      = (u16*)alloc(16384ULL*1024*2);
  u16* XWb      = (u16*)alloc(16384ULL*1024*2);
  u16* enc      = (u16*)alloc(64ULL*256*512*2);
  u16* epb      = (u16*)alloc(64ULL*256*256*2);
  float* hTf    = (float*)alloc(16384ULL*4);
  float* cTf    = (float*)alloc(16384ULL*4);
  float* hTb    = (float*)alloc(16384ULL*4);
  float* cTb    = (float*)alloc(16384ULL*4);
  float* c0g    = (float*)alloc(16384ULL*4);
  float* c1g    = (float*)alloc(16384ULL*4);
  u16* h0buf    = (u16*)alloc(2ULL*16384*2);
  u16* h1buf    = (u16*)alloc(2ULL*16384*2);
  u16* ctxg     = (u16*)alloc(64ULL*512*2);
  float* scoreg = (float*)alloc(16384ULL*4);
  u16* hx       = (u16*)alloc(16ULL*2*16*128*2);
  u16* dout     = (u16*)alloc(4096ULL*256*2);
  if (off > ws_size) return;

  hipMemsetAsync(dcnt, 0, 1024, stream);
  hipMemsetAsync(ecnt, 0, 2048, stream);

  prep_kernel<<<43008, 256, 0, stream>>>(encfWih, encfWhh, encbWih, encbWhh,
      d0Wih, d0Whh, d1Wih, d1Whh, attnW, projW,
      oWihf, oWhhf, oWihb, oWhhb, oW0, oW1, oWaH, oWaE, oprojW);

  gather_kernel<<<20480, 256, 0, stream>>>(src, tgt, src_emb, tgt_emb, xs, temb);

  gemm64<256,1><<<dim3(256,16), 256, 0, stream>>>(xs, 256, oWihf, 256, encfb, XWf, 1024);
  gemm64<256,1><<<dim3(256,16), 256, 0, stream>>>(xs, 256, oWihb, 256, encbb, XWb, 1024);

  encoder_kernel<<<16, 512, 0, stream>>>(XWf, XWb, oWhhf, oWhhb, enc, hTf, cTf, hTb, cTb, hx, ecnt);

  gemm64<512,1><<<dim3(256,4), 256, 0, stream>>>(enc, 512, oWaE, 512, attnb, epb, 256);

  init_states<<<64, 256, 0, stream>>>(hTf, hTb, cTf, cTb, c0g, c1g, h0buf, h1buf);

  decoder_kernel<<<128, 512, 0, stream>>>(epb, enc, temb, oWaH, oW0, oW1,
      attnv, d0b, d1b, c0g, c1g, h0buf, h1buf, ctxg, scoreg, dout, dcnt);

  gemm64<256,0><<<dim3(64,500), 256, 0, stream>>>(dout, 256, oprojW, 256, projb, (float*)d_out, 32000);
}